// Round 6
// baseline (125.770 us; speedup 1.0000x reference)
//
#include <hip/hip_runtime.h>

// T=8192 frames, D=256, P=64 phones, K=128 centers/phone
#define T_FRAMES 8192
#define D_DIM    256
#define P_PHONES 64
#define K_CENT   128
#define TILE_F   16
#define SLOTS_PP 16          // 256 bucket positions / 16 frames per block
#define MARGIN   1.0f        // f16 coarse d2 error bound (worst ~0.4) -> 2.5x headroom
#define NC_MAX   4           // candidate-list cap; tc>4 falls back to full scan

typedef _Float16 half8 __attribute__((ext_vector_type(8)));
typedef float    f32x4 __attribute__((ext_vector_type(4)));

// Single fused kernel. block = one 16-frame tile x 128 centers of one phone.
// Phase 1: in-block bucketing — per-lane scan of phones[] (8 int4 each) +
//          wave shfl_up prefix + cross-wave LDS prefix -> this block's 16
//          frames in ascending order (deterministic partition across blocks).
// Phase 2: A rows (fp32 h, -2 folded) and B pool (fp32 centers) converted to
//          f16 in-register; ||c||^2 computed from fp32 B and parked in LDS.
// Phase 3: f16 MFMA coarse d2 (C-init = ||c||^2), candidate collect (cap 4),
//          exact fp32 rescue on candidates only, parallel copy-out.
__global__ __launch_bounds__(256, 4) void qr_fused_kernel(const float* __restrict__ h,
                                                          const float* __restrict__ centers,
                                                          const int* __restrict__ phones,
                                                          float* __restrict__ out) {
    __shared__ int   sWT[4];
    __shared__ int   sFid[TILE_F];
    __shared__ float sNorm[K_CENT];
    __shared__ float sMin[4][TILE_F];
    __shared__ int   sNc[TILE_F];
    __shared__ int   sCl[TILE_F][NC_MAX];
    __shared__ int   sWin[TILE_F];
    __shared__ int   sRl[TILE_F];
    __shared__ int   sRn;

    const int bid  = blockIdx.x;
    const int slot = ((bid & 7) << 7) | (bid >> 3);   // bijective: all 16 slots of a phone on one XCD
    const int p    = slot >> 4;
    const int wlo  = (slot & 15) << 4;                // this block's bucket window [wlo, wlo+16)

    const int tid  = threadIdx.x;
    const int wave = tid >> 6;
    const int lane = tid & 63;
    const int m    = lane & 15;
    const int quad = lane >> 4;

    if (tid == 0) sRn = 0;
    if (tid < TILE_F) sNc[tid] = 0;

    // ---------- Phase 1: in-block bucketing ----------
    const int fbase = wave * 2048 + lane * 32;        // lane covers frames [fbase, fbase+32)
    int4 pq[8];
#pragma unroll
    for (int q = 0; q < 8; ++q) pq[q] = ((const int4*)(phones + fbase))[q];
    int cl = 0;
#pragma unroll
    for (int q = 0; q < 8; ++q)
        cl += (pq[q].x == p) + (pq[q].y == p) + (pq[q].z == p) + (pq[q].w == p);
    int scan = cl;                                    // inclusive prefix over lanes
#pragma unroll
    for (int off = 1; off < 64; off <<= 1) {
        const int t = __shfl_up(scan, off, 64);
        if (lane >= off) scan += t;
    }
    if (lane == 63) sWT[wave] = scan;
    __syncthreads();
    int bb = 0, T = 0;
#pragma unroll
    for (int w2 = 0; w2 < 4; ++w2) { const int v = sWT[w2]; T += v; if (w2 < wave) bb += v; }
    {
        int run = bb + (scan - cl);                   // global ascending position of my first match
        const int whi = wlo + TILE_F;
#define QR_STEP(VV, FOFF) { if ((VV) == p) { if (run >= wlo && run < whi) sFid[run - wlo] = fbase + (FOFF); ++run; } }
#pragma unroll
        for (int q = 0; q < 8; ++q) {
            QR_STEP(pq[q].x, q * 4 + 0)
            QR_STEP(pq[q].y, q * 4 + 1)
            QR_STEP(pq[q].z, q * 4 + 2)
            QR_STEP(pq[q].w, q * 4 + 3)
        }
#undef QR_STEP
    }
    __syncthreads();
    const int fcnt = min(max(T - wlo, 0), TILE_F);
    if (fcnt == 0) return;                            // block-uniform exit

    // ---------- Phase 2: operands in-register ----------
    const int fiA = sFid[min(m, fcnt - 1)];           // A row m (clamped pad, always valid)

    half8 aF[8];
    {
        const float* ap = h + (size_t)fiA * D_DIM + quad * 8;
#pragma unroll
        for (int s = 0; s < 8; ++s) {                 // -2 folded (exact pow2 scale)
            const float4 l4 = *(const float4*)(ap + s * 32);
            const float4 h4 = *(const float4*)(ap + s * 32 + 4);
            half8 t;
            t[0] = (_Float16)(-2.f * l4.x); t[1] = (_Float16)(-2.f * l4.y);
            t[2] = (_Float16)(-2.f * l4.z); t[3] = (_Float16)(-2.f * l4.w);
            t[4] = (_Float16)(-2.f * h4.x); t[5] = (_Float16)(-2.f * h4.y);
            t[6] = (_Float16)(-2.f * h4.z); t[7] = (_Float16)(-2.f * h4.w);
            aF[s] = t;
        }
    }

    half8 bF[2][8];
    float nrm0 = 0.f, nrm1 = 0.f;
#pragma unroll
    for (int ch = 0; ch < 2; ++ch) {
        const float* bp = centers + ((size_t)((p << 7) + (wave << 5) + ch * 16 + m)) * D_DIM + quad * 8;
        float accn = 0.f;
#pragma unroll
        for (int s = 0; s < 8; ++s) {
            const float4 l4 = *(const float4*)(bp + s * 32);
            const float4 h4 = *(const float4*)(bp + s * 32 + 4);
            half8 t;
            t[0] = (_Float16)l4.x; t[1] = (_Float16)l4.y;
            t[2] = (_Float16)l4.z; t[3] = (_Float16)l4.w;
            t[4] = (_Float16)h4.x; t[5] = (_Float16)h4.y;
            t[6] = (_Float16)h4.z; t[7] = (_Float16)h4.w;
            bF[ch][s] = t;
            accn += l4.x * l4.x + l4.y * l4.y + l4.z * l4.z + l4.w * l4.w
                  + h4.x * h4.x + h4.y * h4.y + h4.z * h4.z + h4.w * h4.w;
        }
        accn += __shfl_xor(accn, 16, 64);             // reduce over quad group -> full ||c||^2
        accn += __shfl_xor(accn, 32, 64);
        if (ch == 0) nrm0 = accn; else nrm1 = accn;
        if (quad == 0) sNorm[(wave << 5) + ch * 16 + m] = accn;
    }
    __builtin_amdgcn_sched_barrier(0);                // pin loads/converts above MFMA loop

    // ---------- Phase 3: coarse MFMA d2 ----------
    f32x4 acc[2];
    acc[0] = f32x4{nrm0, nrm0, nrm0, nrm0};
    acc[1] = f32x4{nrm1, nrm1, nrm1, nrm1};
#pragma unroll
    for (int s = 0; s < 8; ++s) {
        acc[0] = __builtin_amdgcn_mfma_f32_16x16x32_f16(aF[s], bF[0][s], acc[0], 0, 0, 0);
        acc[1] = __builtin_amdgcn_mfma_f32_16x16x32_f16(aF[s], bF[1][s], acc[1], 0, 0, 0);
    }

    // per-frame partial min over this wave's 32 centers (16-lane shfl groups)
#pragma unroll
    for (int r = 0; r < 4; ++r) {
        float mn = fminf(acc[0][r], acc[1][r]);
#pragma unroll
        for (int off = 1; off <= 8; off <<= 1) mn = fminf(mn, __shfl_xor(mn, off, 64));
        if (m == 0) sMin[wave][quad * 4 + r] = mn;
    }
    __syncthreads();

    // global tau per frame; append candidate indices to LDS list (cap NC_MAX)
#pragma unroll
    for (int r = 0; r < 4; ++r) {
        const int f = quad * 4 + r;
        const float gm = fminf(fminf(sMin[0][f], sMin[1][f]), fminf(sMin[2][f], sMin[3][f]));
        const float tau = gm + MARGIN;
#pragma unroll
        for (int ch = 0; ch < 2; ++ch) {
            if (acc[ch][r] < tau) {
                const int pos = atomicAdd(&sNc[f], 1);
                if (pos < NC_MAX) sCl[f][pos] = (wave << 5) + ch * 16 + m;
            }
        }
    }
    __syncthreads();

    // classify: unique candidate -> winner; else enqueue exact rescue
    if (tid < TILE_F) {
        if (sNc[tid] == 1) sWin[tid] = sCl[tid][0];
        else if (tid < fcnt) sRl[atomicAdd(&sRn, 1)] = tid;
    }
    __syncthreads();

    // exact fp32 rescue: one wave per listed frame
    const int rn = sRn;
    for (int ridx = wave; ridx < rn; ridx += 4) {
        const int f2 = sRl[ridx];
        const int fi = sFid[f2];
        const int tc = sNc[f2];
        if (tc <= NC_MAX) {
            // candidate path: h-row + <=4 center rows in ONE latency exposure
            int cnd[NC_MAX];
            cnd[0] = sCl[f2][0];
#pragma unroll
            for (int k = 1; k < NC_MAX; ++k) cnd[k] = (k < tc) ? sCl[f2][k] : cnd[0];
            const float4 hv = ((const float4*)(h + (size_t)fi * D_DIM))[lane];
            float4 cv[NC_MAX];
#pragma unroll
            for (int k = 0; k < NC_MAX; ++k)
                cv[k] = ((const float4*)(centers + ((size_t)(p << 7) + cnd[k]) * D_DIM))[lane];
            float s[NC_MAX];
#pragma unroll
            for (int k = 0; k < NC_MAX; ++k)
                s[k] = hv.x * cv[k].x + hv.y * cv[k].y + hv.z * cv[k].z + hv.w * cv[k].w;
#pragma unroll
            for (int off = 1; off < 64; off <<= 1)
#pragma unroll
                for (int k = 0; k < NC_MAX; ++k) s[k] += __shfl_xor(s[k], off, 64);
            float best = sNorm[cnd[0]] - 2.f * s[0];
            int   bc   = cnd[0];
#pragma unroll
            for (int k = 1; k < NC_MAX; ++k) {        // lex (d2, c) min -> jnp tie rule
                const float dk = sNorm[cnd[k]] - 2.f * s[k];
                if (dk < best || (dk == best && cnd[k] < bc)) { best = dk; bc = cnd[k]; }
            }
            if (lane == 0) sWin[f2] = bc;
        } else {
            // fallback: full 128-center scan (~never taken)
            const float4* hp  = (const float4*)(h + (size_t)fi * D_DIM);
            const float4* cp0 = (const float4*)(centers + ((size_t)(p << 7) + lane) * D_DIM);
            float s0 = 0.f, s1 = 0.f;
#pragma unroll 4
            for (int jx = 0; jx < 64; ++jx) {
                const float4 a  = hp[jx];
                const float4 b0 = cp0[jx];
                const float4 b1 = cp0[jx + 4096];      // center row lane+64
                s0 += a.x * b0.x + a.y * b0.y + a.z * b0.z + a.w * b0.w;
                s1 += a.x * b1.x + a.y * b1.y + a.z * b1.z + a.w * b1.w;
            }
            float best = sNorm[lane] - 2.f * s0;
            int   bc   = lane;
            const float d1 = sNorm[lane + 64] - 2.f * s1;
            if (d1 < best) { best = d1; bc = lane + 64; }
#pragma unroll
            for (int off = 1; off < 64; off <<= 1) {
                const float ob = __shfl_xor(best, off, 64);
                const int   oc = __shfl_xor(bc, off, 64);
                if (ob < best || (ob == best && oc < bc)) { best = ob; bc = oc; }
            }
            if (lane == 0) sWin[f2] = bc;
        }
    }
    __syncthreads();

    // copy winning rows: 16 threads/frame, 4 float4 each
    const int f = tid >> 4, part = tid & 15;
    if (f < fcnt) {
        const int fo = sFid[f];
        const float4* src = (const float4*)(centers + ((size_t)(p << 7) + sWin[f]) * D_DIM);
        float4*       dst = (float4*)(out + (size_t)fo * D_DIM);
#pragma unroll
        for (int jx = 0; jx < 4; ++jx) dst[part + 16 * jx] = src[part + 16 * jx];
    }
}

extern "C" void kernel_launch(void* const* d_in, const int* in_sizes, int n_in,
                              void* d_out, int out_size, void* d_ws, size_t ws_size,
                              hipStream_t stream) {
    const float* h       = (const float*)d_in[0];
    const float* centers = (const float*)d_in[1];
    const int*   phones  = (const int*)d_in[2];
    float*       out     = (float*)d_out;
    (void)d_ws; (void)ws_size;

    qr_fused_kernel<<<P_PHONES * SLOTS_PP, 256, 0, stream>>>(h, centers, phones, out);
}

// Round 8
// 106.756 us; speedup vs baseline: 1.1781x; 1.1781x over previous
//
#include <hip/hip_runtime.h>

// T=8192 frames, D=256, P=64 phones, K=128 centers/phone
#define T_FRAMES 8192
#define D_DIM    256
#define P_PHONES 64
#define K_CENT   128
#define TILE_F   16
#define SLOTS_PP 16          // 256 bucket positions / 16 frames per block
#define MARGIN   1.0f        // f16 coarse d2 error bound (worst ~0.4) -> 2.5x headroom
#define NC_MAX   4           // candidate-list cap; tc>4 falls back to full scan

typedef _Float16 half8 __attribute__((ext_vector_type(8)));
typedef float    f32x4 __attribute__((ext_vector_type(4)));

// Single fused kernel. block = one 16-frame tile x 128 centers of one phone.
// Phase 1: in-block bucketing (per-lane phones scan + wave/LDS prefix).
// Phase 2+3: A converted fp32->f16 in-register (-2 folded); B handled in TWO
//            sequential scoped 16-center chunks (load+convert+norm -> MFMA) to
//            keep peak VGPR pressure < 128 (r6 spilled: 68MB scratch writes).
// Then: candidate collect (cap 4), exact fp32 rescue on candidates, copy-out.
__global__ __launch_bounds__(256, 4) void qr_fused_kernel(const float* __restrict__ h,
                                                          const float* __restrict__ centers,
                                                          const int* __restrict__ phones,
                                                          float* __restrict__ out) {
    __shared__ int   sWT[4];
    __shared__ int   sFid[TILE_F];
    __shared__ float sNorm[K_CENT];
    __shared__ float sMin[4][TILE_F];
    __shared__ int   sNc[TILE_F];
    __shared__ int   sCl[TILE_F][NC_MAX];
    __shared__ int   sWin[TILE_F];
    __shared__ int   sRl[TILE_F];
    __shared__ int   sRn;

    const int bid  = blockIdx.x;
    const int slot = ((bid & 7) << 7) | (bid >> 3);   // bijective: all 16 slots of a phone on one XCD
    const int p    = slot >> 4;
    const int wlo  = (slot & 15) << 4;                // this block's bucket window [wlo, wlo+16)

    const int tid  = threadIdx.x;
    const int wave = tid >> 6;
    const int lane = tid & 63;
    const int m    = lane & 15;
    const int quad = lane >> 4;

    if (tid == 0) sRn = 0;
    if (tid < TILE_F) sNc[tid] = 0;

    // ---------- Phase 1: in-block bucketing ----------
    const int fbase = wave * 2048 + lane * 32;        // lane covers frames [fbase, fbase+32)
    int4 pq[8];
#pragma unroll
    for (int q = 0; q < 8; ++q) pq[q] = ((const int4*)(phones + fbase))[q];
    int cl = 0;
#pragma unroll
    for (int q = 0; q < 8; ++q)
        cl += (pq[q].x == p) + (pq[q].y == p) + (pq[q].z == p) + (pq[q].w == p);
    int scan = cl;                                    // inclusive prefix over lanes
#pragma unroll
    for (int off = 1; off < 64; off <<= 1) {
        const int t = __shfl_up(scan, off, 64);
        if (lane >= off) scan += t;
    }
    if (lane == 63) sWT[wave] = scan;
    __syncthreads();
    int bb = 0, T = 0;
#pragma unroll
    for (int w2 = 0; w2 < 4; ++w2) { const int v = sWT[w2]; T += v; if (w2 < wave) bb += v; }
    {
        int run = bb + (scan - cl);                   // global ascending position of my first match
        const int whi = wlo + TILE_F;
#define QR_STEP(VV, FOFF) { if ((VV) == p) { if (run >= wlo && run < whi) sFid[run - wlo] = fbase + (FOFF); ++run; } }
#pragma unroll
        for (int q = 0; q < 8; ++q) {
            QR_STEP(pq[q].x, q * 4 + 0)
            QR_STEP(pq[q].y, q * 4 + 1)
            QR_STEP(pq[q].z, q * 4 + 2)
            QR_STEP(pq[q].w, q * 4 + 3)
        }
#undef QR_STEP
    }
    __syncthreads();
    const int fcnt = min(max(T - wlo, 0), TILE_F);
    if (fcnt == 0) return;                            // block-uniform exit

    // ---------- Phase 2: A operand in-register ----------
    const int fiA = sFid[min(m, fcnt - 1)];           // A row m (clamped pad, always valid)

    half8 aF[8];
    {
        const float* ap = h + (size_t)fiA * D_DIM + quad * 8;
#pragma unroll
        for (int s = 0; s < 8; ++s) {                 // -2 folded (exact pow2 scale)
            const float4 l4 = *(const float4*)(ap + s * 32);
            const float4 h4 = *(const float4*)(ap + s * 32 + 4);
            half8 t;
            t[0] = (_Float16)(-2.f * l4.x); t[1] = (_Float16)(-2.f * l4.y);
            t[2] = (_Float16)(-2.f * l4.z); t[3] = (_Float16)(-2.f * l4.w);
            t[4] = (_Float16)(-2.f * h4.x); t[5] = (_Float16)(-2.f * h4.y);
            t[6] = (_Float16)(-2.f * h4.z); t[7] = (_Float16)(-2.f * h4.w);
            aF[s] = t;
        }
    }

    // ---------- Phase 3: B in two sequential scoped chunks (spill control) ----
    f32x4 acc0, acc1;
    {   // chunk 0: centers (wave*32 + m)
        const float* bp = centers + ((size_t)((p << 7) + (wave << 5) + m)) * D_DIM + quad * 8;
        half8 bF[8];
        float accn = 0.f;
#pragma unroll
        for (int s = 0; s < 8; ++s) {
            const float4 l4 = *(const float4*)(bp + s * 32);
            const float4 h4 = *(const float4*)(bp + s * 32 + 4);
            half8 t;
            t[0] = (_Float16)l4.x; t[1] = (_Float16)l4.y;
            t[2] = (_Float16)l4.z; t[3] = (_Float16)l4.w;
            t[4] = (_Float16)h4.x; t[5] = (_Float16)h4.y;
            t[6] = (_Float16)h4.z; t[7] = (_Float16)h4.w;
            bF[s] = t;
            accn += l4.x * l4.x + l4.y * l4.y + l4.z * l4.z + l4.w * l4.w
                  + h4.x * h4.x + h4.y * h4.y + h4.z * h4.z + h4.w * h4.w;
        }
        accn += __shfl_xor(accn, 16, 64);             // reduce over quad group -> full ||c||^2
        accn += __shfl_xor(accn, 32, 64);
        if (quad == 0) sNorm[(wave << 5) + m] = accn;
        __builtin_amdgcn_sched_barrier(0);            // pin chunk-0 loads above its MFMAs
        acc0 = f32x4{accn, accn, accn, accn};
#pragma unroll
        for (int s = 0; s < 8; ++s)
            acc0 = __builtin_amdgcn_mfma_f32_16x16x32_f16(aF[s], bF[s], acc0, 0, 0, 0);
    }
    __builtin_amdgcn_sched_barrier(0);                // keep chunk-1 loads below chunk-0 MFMAs
    {   // chunk 1: centers (wave*32 + 16 + m)
        const float* bp = centers + ((size_t)((p << 7) + (wave << 5) + 16 + m)) * D_DIM + quad * 8;
        half8 bF[8];
        float accn = 0.f;
#pragma unroll
        for (int s = 0; s < 8; ++s) {
            const float4 l4 = *(const float4*)(bp + s * 32);
            const float4 h4 = *(const float4*)(bp + s * 32 + 4);
            half8 t;
            t[0] = (_Float16)l4.x; t[1] = (_Float16)l4.y;
            t[2] = (_Float16)l4.z; t[3] = (_Float16)l4.w;
            t[4] = (_Float16)h4.x; t[5] = (_Float16)h4.y;
            t[6] = (_Float16)h4.z; t[7] = (_Float16)h4.w;
            bF[s] = t;
            accn += l4.x * l4.x + l4.y * l4.y + l4.z * l4.z + l4.w * l4.w
                  + h4.x * h4.x + h4.y * h4.y + h4.z * h4.z + h4.w * h4.w;
        }
        accn += __shfl_xor(accn, 16, 64);
        accn += __shfl_xor(accn, 32, 64);
        if (quad == 0) sNorm[(wave << 5) + 16 + m] = accn;
        __builtin_amdgcn_sched_barrier(0);            // pin chunk-1 loads above its MFMAs
        acc1 = f32x4{accn, accn, accn, accn};
#pragma unroll
        for (int s = 0; s < 8; ++s)
            acc1 = __builtin_amdgcn_mfma_f32_16x16x32_f16(aF[s], bF[s], acc1, 0, 0, 0);
    }

    // per-frame partial min over this wave's 32 centers (16-lane shfl groups)
#pragma unroll
    for (int r = 0; r < 4; ++r) {
        float mn = fminf(acc0[r], acc1[r]);
#pragma unroll
        for (int off = 1; off <= 8; off <<= 1) mn = fminf(mn, __shfl_xor(mn, off, 64));
        if (m == 0) sMin[wave][quad * 4 + r] = mn;
    }
    __syncthreads();

    // global tau per frame; append candidate indices to LDS list (cap NC_MAX)
#pragma unroll
    for (int r = 0; r < 4; ++r) {
        const int f = quad * 4 + r;
        const float gm = fminf(fminf(sMin[0][f], sMin[1][f]), fminf(sMin[2][f], sMin[3][f]));
        const float tau = gm + MARGIN;
        if (acc0[r] < tau) {
            const int pos = atomicAdd(&sNc[f], 1);
            if (pos < NC_MAX) sCl[f][pos] = (wave << 5) + m;
        }
        if (acc1[r] < tau) {
            const int pos = atomicAdd(&sNc[f], 1);
            if (pos < NC_MAX) sCl[f][pos] = (wave << 5) + 16 + m;
        }
    }
    __syncthreads();

    // classify: unique candidate -> winner; else enqueue exact rescue
    if (tid < TILE_F) {
        if (sNc[tid] == 1) sWin[tid] = sCl[tid][0];
        else if (tid < fcnt) sRl[atomicAdd(&sRn, 1)] = tid;
    }
    __syncthreads();

    // exact fp32 rescue: one wave per listed frame
    const int rn = sRn;
    for (int ridx = wave; ridx < rn; ridx += 4) {
        const int f2 = sRl[ridx];
        const int fi = sFid[f2];
        const int tc = sNc[f2];
        if (tc <= NC_MAX) {
            // candidate path: h-row + <=4 center rows in ONE latency exposure
            int cnd[NC_MAX];
            cnd[0] = sCl[f2][0];
#pragma unroll
            for (int k = 1; k < NC_MAX; ++k) cnd[k] = (k < tc) ? sCl[f2][k] : cnd[0];
            const float4 hv = ((const float4*)(h + (size_t)fi * D_DIM))[lane];
            float4 cv[NC_MAX];
#pragma unroll
            for (int k = 0; k < NC_MAX; ++k)
                cv[k] = ((const float4*)(centers + ((size_t)(p << 7) + cnd[k]) * D_DIM))[lane];
            float s[NC_MAX];
#pragma unroll
            for (int k = 0; k < NC_MAX; ++k)
                s[k] = hv.x * cv[k].x + hv.y * cv[k].y + hv.z * cv[k].z + hv.w * cv[k].w;
#pragma unroll
            for (int off = 1; off < 64; off <<= 1)
#pragma unroll
                for (int k = 0; k < NC_MAX; ++k) s[k] += __shfl_xor(s[k], off, 64);
            float best = sNorm[cnd[0]] - 2.f * s[0];
            int   bc   = cnd[0];
#pragma unroll
            for (int k = 1; k < NC_MAX; ++k) {        // lex (d2, c) min -> jnp tie rule
                const float dk = sNorm[cnd[k]] - 2.f * s[k];
                if (dk < best || (dk == best && cnd[k] < bc)) { best = dk; bc = cnd[k]; }
            }
            if (lane == 0) sWin[f2] = bc;
        } else {
            // fallback: full 128-center scan (~never taken)
            const float4* hp  = (const float4*)(h + (size_t)fi * D_DIM);
            const float4* cp0 = (const float4*)(centers + ((size_t)(p << 7) + lane) * D_DIM);
            float s0 = 0.f, s1 = 0.f;
#pragma unroll 4
            for (int jx = 0; jx < 64; ++jx) {
                const float4 a  = hp[jx];
                const float4 b0 = cp0[jx];
                const float4 b1 = cp0[jx + 4096];      // center row lane+64
                s0 += a.x * b0.x + a.y * b0.y + a.z * b0.z + a.w * b0.w;
                s1 += a.x * b1.x + a.y * b1.y + a.z * b1.z + a.w * b1.w;
            }
            float best = sNorm[lane] - 2.f * s0;
            int   bc   = lane;
            const float d1 = sNorm[lane + 64] - 2.f * s1;
            if (d1 < best) { best = d1; bc = lane + 64; }
#pragma unroll
            for (int off = 1; off < 64; off <<= 1) {
                const float ob = __shfl_xor(best, off, 64);
                const int   oc = __shfl_xor(bc, off, 64);
                if (ob < best || (ob == best && oc < bc)) { best = ob; bc = oc; }
            }
            if (lane == 0) sWin[f2] = bc;
        }
    }
    __syncthreads();

    // copy winning rows: 16 threads/frame, 4 float4 each
    const int f = tid >> 4, part = tid & 15;
    if (f < fcnt) {
        const int fo = sFid[f];
        const float4* src = (const float4*)(centers + ((size_t)(p << 7) + sWin[f]) * D_DIM);
        float4*       dst = (float4*)(out + (size_t)fo * D_DIM);
#pragma unroll
        for (int jx = 0; jx < 4; ++jx) dst[part + 16 * jx] = src[part + 16 * jx];
    }
}

extern "C" void kernel_launch(void* const* d_in, const int* in_sizes, int n_in,
                              void* d_out, int out_size, void* d_ws, size_t ws_size,
                              hipStream_t stream) {
    const float* h       = (const float*)d_in[0];
    const float* centers = (const float*)d_in[1];
    const int*   phones  = (const int*)d_in[2];
    float*       out     = (float*)d_out;
    (void)d_ws; (void)ws_size;

    qr_fused_kernel<<<P_PHONES * SLOTS_PP, 256, 0, stream>>>(h, centers, phones, out);
}

// Round 9
// 94.947 us; speedup vs baseline: 1.3246x; 1.1244x over previous
//
#include <hip/hip_runtime.h>

// T=8192 frames, D=256, P=64 phones, K=128 centers/phone
#define T_FRAMES 8192
#define D_DIM    256
#define P_PHONES 64
#define K_CENT   128
#define TILE_F   32          // frames per block (r0-proven geometry: halves B redundancy)
#define BUCKET_CAP 256       // max per-phone count ~128+11sigma, safe
#define SLOTS_PP   8         // 256/32 slots per phone
#define MARGIN   1.0f        // f16 coarse d2 error bound (worst ~0.4) -> 2.5x headroom
#define NC_MAX   4           // candidate-list cap; tc>4 falls back to full scan

// ws byte layout
#define WS_NORMS  0                      // float[8192]            32 KB
#define WS_FIDX   32768                  // int[64*256]            64 KB
#define WS_SCNT   98304                  // int[512]                2 KB
#define WS_CH     102400                 // _Float16[64*128*256]    4 MB

typedef _Float16 half8 __attribute__((ext_vector_type(8)));
typedef float    f32x4 __attribute__((ext_vector_type(4)));

// ---------------- K1: prep (centers only — h is consumed fp32 by main) -------
// b 0..127:   convert centers->f16 (cH) + fused fp32 row norms
// b 128..191: bucket block for phone j = b-128; pads fidx to 256 with a valid
//             frame of the same phone; writes flat slotcnt[]
__global__ __launch_bounds__(1024) void qr_prep_kernel(const float* __restrict__ centers,
                                                       const int* __restrict__ phones,
                                                       float* __restrict__ norms,
                                                       int* __restrict__ fidx,
                                                       int* __restrict__ slotcnt,
                                                       _Float16* __restrict__ cH) {
    const int b    = blockIdx.x;
    const int tid  = threadIdx.x;
    const int w    = tid >> 6;
    const int lane = tid & 63;

    if (b < 128) {   // 64 center rows per block; wave w slice k covers row k*16+w
#pragma unroll
        for (int k = 0; k < 4; ++k) {
            const size_t e = (size_t)b * 16384 + (size_t)k * 4096 + (size_t)tid * 4;
            const float4 v = *(const float4*)(centers + e);
            union { _Float16 hf[4]; uint2 u; } pk;
            pk.hf[0] = (_Float16)v.x; pk.hf[1] = (_Float16)v.y;
            pk.hf[2] = (_Float16)v.z; pk.hf[3] = (_Float16)v.w;
            *(uint2*)(cH + e) = pk.u;
            float s = v.x * v.x + v.y * v.y + v.z * v.z + v.w * v.w;
#pragma unroll
            for (int off = 32; off; off >>= 1) s += __shfl_xor(s, off, 64);
            if (lane == 0) norms[b * 64 + k * 16 + w] = s;
        }
        return;
    }

    // bucket block: 16 waves, wave w scans frames [w*512, w*512+512)
    __shared__ int nsh;
    __shared__ int sF0;
    const int j = b - 128;
    if (tid == 0) { nsh = 0; sF0 = 0; }
    __syncthreads();
#pragma unroll
    for (int ch = 0; ch < 8; ++ch) {
        const int f = w * 512 + ch * 64 + lane;
        const bool mt = (phones[f] == j);
        const unsigned long long mask = __ballot(mt);
        const int cnt = __popcll(mask);
        if (cnt) {
            int base = 0;
            if (lane == 0) base = atomicAdd(&nsh, cnt);
            base = __shfl(base, 0, 64);
            if (mt) {
                const int pos = base + __popcll(mask & ((1ull << lane) - 1ull));
                if (pos < BUCKET_CAP) fidx[j * BUCKET_CAP + pos] = f;
                if (pos == 0) sF0 = f;
            }
        }
    }
    __syncthreads();
    const int c = nsh > BUCKET_CAP ? BUCKET_CAP : nsh;
    const int f0 = sF0;
    for (int pos = c + tid; pos < BUCKET_CAP; pos += 1024) fidx[j * BUCKET_CAP + pos] = f0;
    if (tid < SLOTS_PP) {
        const int rem = c - tid * TILE_F;
        slotcnt[j * SLOTS_PP + tid] = rem < 0 ? 0 : (rem > TILE_F ? TILE_F : rem);
    }
}

// ---------------- K2: main ----------------
// block = 32-frame tile x 128 centers; wave w owns centers [w*32, w*32+32).
// A: two 16-frame tiles converted fp32->f16 in-register (-2 folded), scoped to
// cap VGPR peak (r8-proven pattern). B: f16 from cH in two scoped 16-center
// chunks; ||c||^2 is MFMA C-init so acc IS coarse d2. NC<=4 candidate rescue.
__global__ __launch_bounds__(256, 4) void qr_main_kernel(const float* __restrict__ h,
                                                         const float* __restrict__ centers,
                                                         const float* __restrict__ norms,
                                                         const int* __restrict__ fidx,
                                                         const int* __restrict__ slotcnt,
                                                         const _Float16* __restrict__ cH,
                                                         float* __restrict__ out) {
    __shared__ float sMin[4][TILE_F];
    __shared__ int   sNc[TILE_F];
    __shared__ int   sCl[TILE_F][NC_MAX];
    __shared__ int   sWin[TILE_F];
    __shared__ int   sRl[TILE_F];
    __shared__ int   sRn;

    const int bid  = blockIdx.x;
    const int slot = ((bid & 7) << 6) | (bid >> 3);   // bijective: all 8 slots of a phone on one XCD
    const int p    = slot >> 3;
    const int base = (p << 8) + (slot & 7) * TILE_F;  // fidx base for this 32-frame window

    const int tid  = threadIdx.x;
    const int wave = tid >> 6;
    const int lane = tid & 63;
    const int m    = lane & 15;
    const int quad = lane >> 4;

    if (tid == 0) sRn = 0;
    if (tid < TILE_F) sNc[tid] = 0;

    // level-1 loads in parallel: slot count + both tile frame indices (padded -> valid)
    const int fcnt = slotcnt[slot];
    const int fi0  = fidx[base + m];
    const int fi1  = fidx[base + 16 + m];
    if (fcnt == 0) return;                            // block-uniform exit

    // ---------- A tiles: fp32 -> f16 in-register, -2 folded, scoped per tile ----
    half8 aF0[8], aF1[8];
    {
        const float* ap = h + (size_t)fi0 * D_DIM + quad * 8;
#pragma unroll
        for (int s = 0; s < 8; ++s) {
            const float4 l4 = *(const float4*)(ap + s * 32);
            const float4 h4 = *(const float4*)(ap + s * 32 + 4);
            half8 t;
            t[0] = (_Float16)(-2.f * l4.x); t[1] = (_Float16)(-2.f * l4.y);
            t[2] = (_Float16)(-2.f * l4.z); t[3] = (_Float16)(-2.f * l4.w);
            t[4] = (_Float16)(-2.f * h4.x); t[5] = (_Float16)(-2.f * h4.y);
            t[6] = (_Float16)(-2.f * h4.z); t[7] = (_Float16)(-2.f * h4.w);
            aF0[s] = t;
        }
    }
    __builtin_amdgcn_sched_barrier(0);                // cap transient pressure between tiles
    {
        const float* ap = h + (size_t)fi1 * D_DIM + quad * 8;
#pragma unroll
        for (int s = 0; s < 8; ++s) {
            const float4 l4 = *(const float4*)(ap + s * 32);
            const float4 h4 = *(const float4*)(ap + s * 32 + 4);
            half8 t;
            t[0] = (_Float16)(-2.f * l4.x); t[1] = (_Float16)(-2.f * l4.y);
            t[2] = (_Float16)(-2.f * l4.z); t[3] = (_Float16)(-2.f * l4.w);
            t[4] = (_Float16)(-2.f * h4.x); t[5] = (_Float16)(-2.f * h4.y);
            t[6] = (_Float16)(-2.f * h4.z); t[7] = (_Float16)(-2.f * h4.w);
            aF1[s] = t;
        }
    }
    __builtin_amdgcn_sched_barrier(0);

    // ---------- B chunks: f16, each scoped {load -> MFMA x16} ----------
    f32x4 acc00, acc01, acc10, acc11;                 // acc[tile][chunk]
    {   // chunk 0: center (wave<<5) + m
        const _Float16* bp = cH + (((size_t)(p << 7) + (wave << 5) + m) << 8) + quad * 8;
        half8 bF[8];
#pragma unroll
        for (int s = 0; s < 8; ++s) bF[s] = *(const half8*)(bp + s * 32);
        const float nrm = norms[(p << 7) + (wave << 5) + m];
        __builtin_amdgcn_sched_barrier(0);            // pin chunk loads above its MFMAs
        acc00 = f32x4{nrm, nrm, nrm, nrm};
        acc10 = f32x4{nrm, nrm, nrm, nrm};
#pragma unroll
        for (int s = 0; s < 8; ++s) {
            acc00 = __builtin_amdgcn_mfma_f32_16x16x32_f16(aF0[s], bF[s], acc00, 0, 0, 0);
            acc10 = __builtin_amdgcn_mfma_f32_16x16x32_f16(aF1[s], bF[s], acc10, 0, 0, 0);
        }
    }
    __builtin_amdgcn_sched_barrier(0);
    {   // chunk 1: center (wave<<5) + 16 + m
        const _Float16* bp = cH + (((size_t)(p << 7) + (wave << 5) + 16 + m) << 8) + quad * 8;
        half8 bF[8];
#pragma unroll
        for (int s = 0; s < 8; ++s) bF[s] = *(const half8*)(bp + s * 32);
        const float nrm = norms[(p << 7) + (wave << 5) + 16 + m];
        __builtin_amdgcn_sched_barrier(0);
        acc01 = f32x4{nrm, nrm, nrm, nrm};
        acc11 = f32x4{nrm, nrm, nrm, nrm};
#pragma unroll
        for (int s = 0; s < 8; ++s) {
            acc01 = __builtin_amdgcn_mfma_f32_16x16x32_f16(aF0[s], bF[s], acc01, 0, 0, 0);
            acc11 = __builtin_amdgcn_mfma_f32_16x16x32_f16(aF1[s], bF[s], acc11, 0, 0, 0);
        }
    }

    // per-frame partial min over this wave's 32 centers (16-lane shfl groups)
#pragma unroll
    for (int r = 0; r < 4; ++r) {
        float mn0 = fminf(acc00[r], acc01[r]);        // tile 0, frame quad*4+r
        float mn1 = fminf(acc10[r], acc11[r]);        // tile 1, frame 16+quad*4+r
#pragma unroll
        for (int off = 1; off <= 8; off <<= 1) {
            mn0 = fminf(mn0, __shfl_xor(mn0, off, 64));
            mn1 = fminf(mn1, __shfl_xor(mn1, off, 64));
        }
        if (m == 0) {
            sMin[wave][quad * 4 + r]      = mn0;
            sMin[wave][16 + quad * 4 + r] = mn1;
        }
    }
    __syncthreads();

    // global tau per frame; append candidate indices to LDS list (cap NC_MAX)
#pragma unroll
    for (int r = 0; r < 4; ++r) {
        const int f0f = quad * 4 + r;
        const int f1f = 16 + quad * 4 + r;
        const float gm0 = fminf(fminf(sMin[0][f0f], sMin[1][f0f]), fminf(sMin[2][f0f], sMin[3][f0f]));
        const float gm1 = fminf(fminf(sMin[0][f1f], sMin[1][f1f]), fminf(sMin[2][f1f], sMin[3][f1f]));
        const float tau0 = gm0 + MARGIN;
        const float tau1 = gm1 + MARGIN;
        if (acc00[r] < tau0) { const int pos = atomicAdd(&sNc[f0f], 1); if (pos < NC_MAX) sCl[f0f][pos] = (wave << 5) + m; }
        if (acc01[r] < tau0) { const int pos = atomicAdd(&sNc[f0f], 1); if (pos < NC_MAX) sCl[f0f][pos] = (wave << 5) + 16 + m; }
        if (acc10[r] < tau1) { const int pos = atomicAdd(&sNc[f1f], 1); if (pos < NC_MAX) sCl[f1f][pos] = (wave << 5) + m; }
        if (acc11[r] < tau1) { const int pos = atomicAdd(&sNc[f1f], 1); if (pos < NC_MAX) sCl[f1f][pos] = (wave << 5) + 16 + m; }
    }
    __syncthreads();

    // classify: unique candidate -> winner; else enqueue exact rescue
    if (tid < TILE_F) {
        if (sNc[tid] == 1) sWin[tid] = sCl[tid][0];
        else if (tid < fcnt) sRl[atomicAdd(&sRn, 1)] = tid;
    }
    __syncthreads();

    // exact fp32 rescue: one wave per listed frame
    const int rn = sRn;
    for (int ridx = wave; ridx < rn; ridx += 4) {
        const int f2 = sRl[ridx];
        const int fi = fidx[base + f2];
        const int tc = sNc[f2];
        if (tc <= NC_MAX) {
            // candidate path: h-row + <=4 center rows in ONE latency exposure
            int cnd[NC_MAX];
            cnd[0] = sCl[f2][0];
#pragma unroll
            for (int k = 1; k < NC_MAX; ++k) cnd[k] = (k < tc) ? sCl[f2][k] : cnd[0];
            const float4 hv = ((const float4*)(h + (size_t)fi * D_DIM))[lane];
            float4 cv[NC_MAX];
#pragma unroll
            for (int k = 0; k < NC_MAX; ++k)
                cv[k] = ((const float4*)(centers + ((size_t)(p << 7) + cnd[k]) * D_DIM))[lane];
            float s[NC_MAX];
#pragma unroll
            for (int k = 0; k < NC_MAX; ++k)
                s[k] = hv.x * cv[k].x + hv.y * cv[k].y + hv.z * cv[k].z + hv.w * cv[k].w;
#pragma unroll
            for (int off = 1; off < 64; off <<= 1)
#pragma unroll
                for (int k = 0; k < NC_MAX; ++k) s[k] += __shfl_xor(s[k], off, 64);
            float best = norms[(p << 7) + cnd[0]] - 2.f * s[0];
            int   bc   = cnd[0];
#pragma unroll
            for (int k = 1; k < NC_MAX; ++k) {        // lex (d2, c) min -> jnp tie rule
                const float dk = norms[(p << 7) + cnd[k]] - 2.f * s[k];
                if (dk < best || (dk == best && cnd[k] < bc)) { best = dk; bc = cnd[k]; }
            }
            if (lane == 0) sWin[f2] = bc;
        } else {
            // fallback: full 128-center scan (~never taken)
            const float4* hp  = (const float4*)(h + (size_t)fi * D_DIM);
            const float4* cp0 = (const float4*)(centers + ((size_t)(p << 7) + lane) * D_DIM);
            float s0 = 0.f, s1 = 0.f;
#pragma unroll 4
            for (int jx = 0; jx < 64; ++jx) {
                const float4 a  = hp[jx];
                const float4 b0 = cp0[jx];
                const float4 b1 = cp0[jx + 4096];      // center row lane+64
                s0 += a.x * b0.x + a.y * b0.y + a.z * b0.z + a.w * b0.w;
                s1 += a.x * b1.x + a.y * b1.y + a.z * b1.z + a.w * b1.w;
            }
            float best = norms[(p << 7) + lane] - 2.f * s0;
            int   bc   = lane;
            const float d1 = norms[(p << 7) + lane + 64] - 2.f * s1;
            if (d1 < best) { best = d1; bc = lane + 64; }
#pragma unroll
            for (int off = 1; off < 64; off <<= 1) {
                const float ob = __shfl_xor(best, off, 64);
                const int   oc = __shfl_xor(bc, off, 64);
                if (ob < best || (ob == best && oc < bc)) { best = ob; bc = oc; }
            }
            if (lane == 0) sWin[f2] = bc;
        }
    }
    __syncthreads();

    // copy winning rows: 8 threads/frame, 8 float4 each
    const int f = tid >> 3, part = tid & 7;
    if (f < fcnt) {
        const int fo = fidx[base + f];
        const float4* src = (const float4*)(centers + ((size_t)(p << 7) + sWin[f]) * D_DIM);
        float4*       dst = (float4*)(out + (size_t)fo * D_DIM);
#pragma unroll
        for (int jx = 0; jx < 8; ++jx) dst[part + 8 * jx] = src[part + 8 * jx];
    }
}

extern "C" void kernel_launch(void* const* d_in, const int* in_sizes, int n_in,
                              void* d_out, int out_size, void* d_ws, size_t ws_size,
                              hipStream_t stream) {
    const float* h       = (const float*)d_in[0];
    const float* centers = (const float*)d_in[1];
    const int*   phones  = (const int*)d_in[2];
    float*       out     = (float*)d_out;

    char* ws = (char*)d_ws;
    float*    norms   = (float*)(ws + WS_NORMS);
    int*      fidx    = (int*)(ws + WS_FIDX);
    int*      slotcnt = (int*)(ws + WS_SCNT);
    _Float16* cH      = (_Float16*)(ws + WS_CH);

    qr_prep_kernel<<<192, 1024, 0, stream>>>(centers, phones, norms, fidx, slotcnt, cH);
    qr_main_kernel<<<P_PHONES * SLOTS_PP, 256, 0, stream>>>(h, centers, norms, fidx, slotcnt, cH, out);
}